// Round 1
// baseline (739.397 us; speedup 1.0000x reference)
//
#include <hip/hip_runtime.h>

#define DIN  128
#define DHID 16
#define NCLS 40

// K1: X1 = H @ W1   [n,128]@[128,16] -> [n,16]
__global__ __launch_bounds__(256) void k1_gemm_hw1(
    const float* __restrict__ H, const float* __restrict__ W1,
    float* __restrict__ X1, int n)
{
    __shared__ __align__(16) float w[DIN * DHID];   // 8 KB
    for (int i = threadIdx.x; i < DIN * DHID; i += 256) w[i] = W1[i];
    __syncthreads();
    int r = blockIdx.x * 256 + threadIdx.x;
    if (r >= n) return;
    const float4* hrow = (const float4*)(H + (size_t)r * DIN);
    float acc[DHID];
#pragma unroll
    for (int j = 0; j < DHID; ++j) acc[j] = 0.f;
#pragma unroll 4
    for (int k4 = 0; k4 < DIN / 4; ++k4) {
        float4 h = hrow[k4];
        float hh[4] = {h.x, h.y, h.z, h.w};
#pragma unroll
        for (int kk = 0; kk < 4; ++kk) {
#pragma unroll
            for (int j4 = 0; j4 < DHID / 4; ++j4) {
                float4 wv = *(const float4*)&w[(4 * k4 + kk) * DHID + 4 * j4];
                acc[4 * j4 + 0] += hh[kk] * wv.x;
                acc[4 * j4 + 1] += hh[kk] * wv.y;
                acc[4 * j4 + 2] += hh[kk] * wv.z;
                acc[4 * j4 + 3] += hh[kk] * wv.w;
            }
        }
    }
    float4* o = (float4*)(X1 + (size_t)r * DHID);
#pragma unroll
    for (int q = 0; q < DHID / 4; ++q)
        o[q] = make_float4(acc[4*q], acc[4*q+1], acc[4*q+2], acc[4*q+3]);
}

// K2/K3: dst[row,:] += val * f(src[col,:])  where f = identity or relu(x+b)
// one thread per (edge, j), j in [0,16)
__global__ __launch_bounds__(256) void k2_scatter16(
    const int* __restrict__ rows, const int* __restrict__ cols,
    const float* __restrict__ vals, const float* __restrict__ src,
    const float* __restrict__ bias, int do_relu,
    float* __restrict__ dst, int nnz)
{
    unsigned int tid = blockIdx.x * 256u + threadIdx.x;
    int e = (int)(tid >> 4);
    int j = (int)(tid & 15u);
    if (e >= nnz) return;
    int c = cols[e];
    int r = rows[e];
    float x = src[(size_t)c * DHID + j];
    if (do_relu) x = fmaxf(x + bias[j], 0.f);
    atomicAdd(&dst[(size_t)r * DHID + j], x * vals[e]);
}

// K4: out = log_softmax(relu(T @ W2 + b2))   [n,16]@[16,40]
__global__ __launch_bounds__(256) void k4_final(
    const float* __restrict__ T, const float* __restrict__ W2,
    const float* __restrict__ b2, float* __restrict__ out, int n)
{
    __shared__ __align__(16) float w[DHID * NCLS];  // 640 floats
    __shared__ float bb[NCLS];
    for (int i = threadIdx.x; i < DHID * NCLS; i += 256) w[i] = W2[i];
    if (threadIdx.x < NCLS) bb[threadIdx.x] = b2[threadIdx.x];
    __syncthreads();
    int r = blockIdx.x * 256 + threadIdx.x;
    if (r >= n) return;
    float t[DHID];
    const float4* trow = (const float4*)(T + (size_t)r * DHID);
#pragma unroll
    for (int q = 0; q < DHID / 4; ++q) {
        float4 v = trow[q];
        t[4*q+0] = v.x; t[4*q+1] = v.y; t[4*q+2] = v.z; t[4*q+3] = v.w;
    }
    float o[NCLS];
#pragma unroll
    for (int j = 0; j < NCLS; ++j) o[j] = bb[j];
#pragma unroll 4
    for (int k = 0; k < DHID; ++k) {
        float tk = t[k];
#pragma unroll
        for (int j4 = 0; j4 < NCLS / 4; ++j4) {
            float4 wv = *(const float4*)&w[k * NCLS + 4 * j4];
            o[4*j4+0] += tk * wv.x;
            o[4*j4+1] += tk * wv.y;
            o[4*j4+2] += tk * wv.z;
            o[4*j4+3] += tk * wv.w;
        }
    }
    float m = 0.f;  // relu output >= 0, so max >= 0; init with 0 after relu
#pragma unroll
    for (int j = 0; j < NCLS; ++j) {
        o[j] = fmaxf(o[j], 0.f);
        m = fmaxf(m, o[j]);
    }
    float s = 0.f;
#pragma unroll
    for (int j = 0; j < NCLS; ++j) s += __expf(o[j] - m);
    float ls = m + __logf(s);
    float4* orow = (float4*)(out + (size_t)r * NCLS);
#pragma unroll
    for (int j4 = 0; j4 < NCLS / 4; ++j4)
        orow[j4] = make_float4(o[4*j4+0]-ls, o[4*j4+1]-ls, o[4*j4+2]-ls, o[4*j4+3]-ls);
}

extern "C" void kernel_launch(void* const* d_in, const int* in_sizes, int n_in,
                              void* d_out, int out_size, void* d_ws, size_t ws_size,
                              hipStream_t stream)
{
    const float* H    = (const float*)d_in[0];
    const int*   rows = (const int*)d_in[1];
    const int*   cols = (const int*)d_in[2];
    const float* vals = (const float*)d_in[3];
    const float* W1   = (const float*)d_in[4];
    const float* b1   = (const float*)d_in[5];
    const float* W2   = (const float*)d_in[6];
    const float* b2   = (const float*)d_in[7];
    float* out = (float*)d_out;

    int n   = in_sizes[0] / DIN;   // 200000
    int nnz = in_sizes[1];         // 6.4M

    // workspace: A = X1 then T (n*16 f32), B = S1 (n*16 f32) -> 25.6 MB total
    float* A = (float*)d_ws;
    float* B = A + (size_t)n * DHID;

    int rb = (n + 255) / 256;
    unsigned int sb = (unsigned int)(((long long)nnz * DHID + 255) / 256);

    // X1 = H @ W1
    k1_gemm_hw1<<<rb, 256, 0, stream>>>(H, W1, A, n);
    // S1 = A_sp @ X1
    hipMemsetAsync(B, 0, (size_t)n * DHID * sizeof(float), stream);
    k2_scatter16<<<sb, 256, 0, stream>>>(rows, cols, vals, A, nullptr, 0, B, nnz);
    // T = A_sp @ relu(S1 + b1)   (associativity: A(H1 W2) = (A H1) W2)
    hipMemsetAsync(A, 0, (size_t)n * DHID * sizeof(float), stream);
    k2_scatter16<<<sb, 256, 0, stream>>>(rows, cols, vals, B, b1, 1, A, nnz);
    // out = log_softmax(relu(T @ W2 + b2))
    k4_final<<<rb, 256, 0, stream>>>(A, W2, b2, out, n);
}